// Round 16
// baseline (16912.231 us; speedup 1.0000x reference)
//
#include <hip/hip_runtime.h>
#include <hip/hip_cooperative_groups.h>

namespace cg = cooperative_groups;

typedef short short8 __attribute__((ext_vector_type(8)));
typedef float f32x4  __attribute__((ext_vector_type(4)));
typedef unsigned short us4 __attribute__((ext_vector_type(4)));
typedef unsigned long long u64t;

#define Tn 512
#define NBLK 256
#define NTHR 512

#define MFMA16(A,B,C) __builtin_amdgcn_mfma_f32_16x16x32_bf16(A,B,C,0,0,0)

// ---- LDS layout (ushort units) ----
#define J_UC_HI 0
#define J_UC_LO 16512
#define J_UZ_HI 33024
#define J_UZ_LO 49536
#define J_WZ_HI 66048
#define J_WZ_LO 70272
#define J_EX_US 74496          // float exch here (1024 floats)
#define M_WIH_HI 0
#define M_WIH_LO 3456
#define M_WHH_HI 6912
#define M_WHH_LO 19584
#define M_EX_US 32256          // float exch here (2048 floats)
#define LDS_BYTES 153088

// ---- ws planes (ushort units); each plane 131072, buf p at +p*131072 ----
#define HM_HI 0
#define HM_LO 262144
#define NG_HI 524288
#define NG_LO 786432
#define HJ_HI 1048576
#define HJ_LO 1310720

__device__ __forceinline__ float sigf(float v){ return 1.0f/(1.0f+__expf(-v)); }
__device__ __forceinline__ float tanhfast(float v){
    float ax=fabsf(v); float e=__expf(-2.0f*ax);
    float t=(1.0f-e)/(1.0f+e); return copysignf(t,v);
}
__device__ __forceinline__ unsigned short f2bf(float f){
    union{float f; unsigned u;} v; v.f=f;
    unsigned r = v.u + 0x7FFFu + ((v.u>>16)&1u);
    return (unsigned short)(r>>16);
}
__device__ __forceinline__ float bf2f(unsigned short h){
    union{unsigned u; float f;} w; w.u = ((unsigned)h)<<16; return w.f;
}
__device__ __forceinline__ void cvt8_hilo(const float* p, short8& hi, short8& lo){
    float4 a = *(const float4*)p;
    float4 b = *(const float4*)(p+4);
    float v[8] = {a.x,a.y,a.z,a.w,b.x,b.y,b.z,b.w};
    #pragma unroll
    for (int e = 0; e < 8; ++e) {
        unsigned short h = f2bf(v[e]);
        hi[e] = (short)h;
        lo[e] = (short)f2bf(v[e] - bf2f(h));
    }
}

// ---- agent-scoped (device-coherent, L2-bypassing) state access ----
__device__ __forceinline__ short8 ald16(const unsigned short* p){
    u64t a = __hip_atomic_load((const u64t*)p,     __ATOMIC_RELAXED, __HIP_MEMORY_SCOPE_AGENT);
    u64t b = __hip_atomic_load((const u64t*)(p+4), __ATOMIC_RELAXED, __HIP_MEMORY_SCOPE_AGENT);
    union { u64t q[2]; short8 s; } u;
    u.q[0]=a; u.q[1]=b; return u.s;
}
__device__ __forceinline__ us4 ald8v(const unsigned short* p){
    u64t a = __hip_atomic_load((const u64t*)p, __ATOMIC_RELAXED, __HIP_MEMORY_SCOPE_AGENT);
    union { u64t q; us4 v; } u; u.q=a; return u.v;
}
__device__ __forceinline__ void ast8(unsigned short* p, us4 v){
    union { us4 v; u64t q; } u; u.v=v;
    __hip_atomic_store((u64t*)p, u.q, __ATOMIC_RELAXED, __HIP_MEMORY_SCOPE_AGENT);
}

// ---- point-to-point sync flags (zeroed each call) ----
__device__ int d_mgrp[2][4][513];   // marg blocks done step s per (bh,g): target 16
__device__ int d_jflag[2][513];     // joint blocks done step u per bh: target 64

__device__ __forceinline__ void spin_ge(int* p, int target){
    while (__hip_atomic_load(p, __ATOMIC_RELAXED, __HIP_MEMORY_SCOPE_AGENT) < target)
        __builtin_amdgcn_s_sleep(1);
}

__launch_bounds__(NTHR, 1)
__global__ void mgrn_k(const float* __restrict__ x,
                       const float* __restrict__ w_ih,
                       const float* __restrict__ w_hh,
                       const float* __restrict__ b_ih,
                       const float* __restrict__ u_c,
                       const float* __restrict__ b_c,
                       const float* __restrict__ w_z,
                       const float* __restrict__ u_z,
                       const float* __restrict__ b_z,
                       float* __restrict__ out,
                       float* __restrict__ ws,
                       int s_lo, int s_hi, int coop)
{
    cg::grid_group grid = cg::this_grid();
    extern __shared__ unsigned short lds_us[];

    unsigned short* U = (unsigned short*)ws;
    unsigned int*  U32 = (unsigned int*)ws;

    const int tid  = threadIdx.x;
    const int lane = tid & 63;
    const int wv   = tid >> 6;          // 0..7
    const int tb   = wv & 3;            // b-tile 0..3
    const int hf   = wv >> 2;           // role half
    const int r16  = lane & 15;
    const int q4   = (lane >> 4) * 4;
    const int ko8  = (lane >> 4) * 8;   // k-chunk (shorts)
    const int wg   = blockIdx.x;
    const bool isMarg = (wg < 128);

    if (coop) {   // zero t=-1 (buf 1) hi/lo planes of hm,hj + flags
        int gidx = wg * NTHR + tid;     // [0, 131072)
        if (gidx < 65536) {
            U32[ 65536 + gidx] = 0u;    // HM_HI buf1
            U32[196608 + gidx] = 0u;    // HM_LO buf1
            U32[589824 + gidx] = 0u;    // HJ_HI buf1
            U32[720896 + gidx] = 0u;    // HJ_LO buf1
        }
        int* fm = &d_mgrp[0][0][0];
        if (gidx < 2*4*513) fm[gidx] = 0;
        int* fj = &d_jflag[0][0];
        if (gidx < 2*513) fj[gidx] = 0;
    }

    if (isMarg) {
        // ============ MARGINAL: block = 16 h-rows x 64 batch ============
        const int c  = wg >> 1;
        const int bh = wg & 1;
        const int g  = c >> 4;
        const int h0 = (c & 15) * 16;
        const int bb = bh*64 + tb*16 + r16;   // this lane's batch

        const float* wih_g = w_ih + (size_t)g * 768 * 64;
        const float* whh_g = w_hh + (size_t)g * 768 * 256;
        float* exch = (float*)(lds_us + M_EX_US);

        // ---- stage weights to LDS as hi/lo (rows: gate*16 + (h-h0)) ----
        for (int i = tid; i < 48*64; i += NTHR) {
            int r = i >> 6, k = i & 63;
            int gate = r >> 4, row = r & 15;
            float v = wih_g[(size_t)(gate*256 + h0 + row)*64 + k];
            unsigned short h = f2bf(v);
            lds_us[M_WIH_HI + r*72 + k] = h;
            lds_us[M_WIH_LO + r*72 + k] = f2bf(v - bf2f(h));
        }
        for (int i = tid; i < 48*256; i += NTHR) {
            int r = i >> 8, k = i & 255;
            int gate = r >> 4, row = r & 15;
            float v = whh_g[(size_t)(gate*256 + h0 + row)*256 + k];
            unsigned short h = f2bf(v);
            lds_us[M_WHH_HI + r*264 + k] = h;
            lds_us[M_WHH_LO + r*264 + k] = f2bf(v - bf2f(h));
        }
        __syncthreads();
        if (coop) { grid.sync(); __threadfence(); }   // one-time: init visibility

        const int rAw = hf ? 16 : 0;          // accA gate rows (r / z)

        float br_[4], bz_[4], bn_[4];
        #pragma unroll
        for (int r = 0; r < 4; ++r) {
            int hh = h0 + q4 + r;
            br_[r] = b_ih[g*768 + hh];
            bz_[r] = b_ih[g*768 + 256 + hh];
            bn_[r] = b_ih[g*768 + 512 + hh];
        }

        for (int s = s_lo; s <= s_hi; ++s) {
            if (s < Tn) {
                const int p0 = s & 1, p1 = (s+1) & 1;
                f32x4 aA0={0.f,0.f,0.f,0.f}, aA1={0.f,0.f,0.f,0.f}, aA2={0.f,0.f,0.f,0.f};
                f32x4 aB0={0.f,0.f,0.f,0.f}, aB1={0.f,0.f,0.f,0.f}, aB2={0.f,0.f,0.f,0.f};
                const float* xp = x + ((size_t)s*128 + bb)*256 + g*64;

                // ---- x-part (K=64, pre-spin) ----
                #pragma unroll
                for (int i = 0; i < 2; ++i) {
                    short8 xhi, xlo; cvt8_hilo(xp + i*32 + ko8, xhi, xlo);
                    short8 whi = *(const short8*)(lds_us + M_WIH_HI + (rAw + r16)*72 + i*32 + ko8);
                    short8 wlo = *(const short8*)(lds_us + M_WIH_LO + (rAw + r16)*72 + i*32 + ko8);
                    aA0 = MFMA16(whi, xhi, aA0);
                    aA1 = MFMA16(whi, xlo, aA1);
                    aA2 = MFMA16(wlo, xhi, aA2);
                    if (hf == 0) {
                        short8 nhi = *(const short8*)(lds_us + M_WIH_HI + (32 + r16)*72 + i*32 + ko8);
                        short8 nlo = *(const short8*)(lds_us + M_WIH_LO + (32 + r16)*72 + i*32 + ko8);
                        aB0 = MFMA16(nhi, xhi, aB0);
                        aB1 = MFMA16(nhi, xlo, aB1);
                        aB2 = MFMA16(nlo, xhi, aB2);
                    }
                }

                if (coop) {
                    if (tid == 0) {
                        if (s >= 1) spin_ge(&d_mgrp[bh][g][s-1], 16);
                        if (s >= 2) spin_ge(&d_jflag[bh][s-2], 64);
                    }
                    __syncthreads();
                }

                // ---- h-part (K=256), agent-scoped state loads ----
                {
                    const int hofs = p1*131072 + bb*1024 + g*256;
                    #pragma unroll 2
                    for (int i = 0; i < 8; ++i) {
                        short8 hhi = ald16(U + HM_HI + hofs + i*32 + ko8);
                        short8 hlo = ald16(U + HM_LO + hofs + i*32 + ko8);
                        short8 whi = *(const short8*)(lds_us + M_WHH_HI + (rAw + r16)*264 + i*32 + ko8);
                        short8 wlo = *(const short8*)(lds_us + M_WHH_LO + (rAw + r16)*264 + i*32 + ko8);
                        aA0 = MFMA16(whi, hhi, aA0);
                        aA1 = MFMA16(whi, hlo, aA1);
                        aA2 = MFMA16(wlo, hhi, aA2);
                        if (hf == 1) {
                            short8 nhi = *(const short8*)(lds_us + M_WHH_HI + (32 + r16)*264 + i*32 + ko8);
                            short8 nlo = *(const short8*)(lds_us + M_WHH_LO + (32 + r16)*264 + i*32 + ko8);
                            aB0 = MFMA16(nhi, hhi, aB0);
                            aB1 = MFMA16(nhi, hlo, aB1);
                            aB2 = MFMA16(nlo, hhi, aB2);
                        }
                    }
                }
                f32x4 accA = aA0 + aA1 + aA2;
                f32x4 accB = aB0 + aB1 + aB2;

                if (hf == 1) {
                    #pragma unroll
                    for (int r = 0; r < 4; ++r) {
                        int idx = (q4 + r)*16 + r16;
                        exch[(tb*2 + 0)*256 + idx] = accA[r];   // z partial
                        exch[(tb*2 + 1)*256 + idx] = accB[r];   // hn partial
                    }
                }
                __syncthreads();
                if (hf == 0) {
                    const int kkb = g*256 + h0 + q4;
                    const int o1  = p1*131072 + bb*1024 + kkb;
                    const int o0  = p0*131072 + bb*1024 + kkb;
                    us4 hhi = ald8v(U + HM_HI + o1);
                    us4 hlo = ald8v(U + HM_LO + o1);
                    us4 hmhi, hmlo, nghi, nglo;
                    #pragma unroll
                    for (int r = 0; r < 4; ++r) {
                        int idx = (q4 + r)*16 + r16;
                        float zacc  = exch[(tb*2 + 0)*256 + idx];
                        float hnacc = exch[(tb*2 + 1)*256 + idx];
                        float rg = sigf(accA[r] + br_[r]);
                        float zg = sigf(zacc + bz_[r]);
                        float n  = tanhfast(accB[r] + bn_[r] + rg * hnacc);
                        float hmo = bf2f(hhi[r]) + bf2f(hlo[r]);
                        float hnew = n + zg * (hmo - n);
                        unsigned short h1 = f2bf(hnew);
                        hmhi[r] = h1; hmlo[r] = f2bf(hnew - bf2f(h1));
                        unsigned short h2 = f2bf(n);
                        nghi[r] = h2; nglo[r] = f2bf(n - bf2f(h2));
                    }
                    ast8(U + HM_HI + o0, hmhi);
                    ast8(U + HM_LO + o0, hmlo);
                    ast8(U + NG_HI + o0, nghi);
                    ast8(U + NG_LO + o0, nglo);
                }
                __syncthreads();   // drains vmcnt: scoped stores complete at L3
                if (coop && tid == 0) {
                    atomicAdd(&d_mgrp[bh][g][s], 1);
                }
            }
        }
    } else {
        // ============ JOINT: block = 16 j-rows x 64 batch, 1 step behind ====
        const int wg2 = wg - 128;
        const int j0  = (wg2 >> 1) * 16;
        const int bh  = wg2 & 1;
        const int bb  = bh*64 + tb*16 + r16;
        float* exch = (float*)(lds_us + J_EX_US);

        // ---- stage weights to LDS as hi/lo ----
        for (int i = tid; i < 16*1024; i += NTHR) {
            int r = i >> 10, k = i & 1023;
            float v = u_c[(size_t)(j0 + r)*1024 + k];
            unsigned short h = f2bf(v);
            lds_us[J_UC_HI + r*1032 + k] = h;
            lds_us[J_UC_LO + r*1032 + k] = f2bf(v - bf2f(h));
            v = u_z[(size_t)(j0 + r)*1024 + k];
            h = f2bf(v);
            lds_us[J_UZ_HI + r*1032 + k] = h;
            lds_us[J_UZ_LO + r*1032 + k] = f2bf(v - bf2f(h));
        }
        for (int i = tid; i < 16*256; i += NTHR) {
            int r = i >> 8, k = i & 255;
            float v = w_z[(size_t)(j0 + r)*256 + k];
            unsigned short h = f2bf(v);
            lds_us[J_WZ_HI + r*264 + k] = h;
            lds_us[J_WZ_LO + r*264 + k] = f2bf(v - bf2f(h));
        }
        __syncthreads();
        if (coop) { grid.sync(); __threadfence(); }   // one-time: init visibility

        float bc_[4], bzj_[4];
        #pragma unroll
        for (int r = 0; r < 4; ++r) {
            int jj = j0 + q4 + r;
            bc_[r]  = b_c[jj];
            bzj_[r] = b_z[jj];
        }

        for (int s = s_lo; s <= s_hi; ++s) {
            if (s >= 1) {
                const int u  = s - 1;
                const int p0 = u & 1, p1 = (u+1) & 1;
                f32x4 a0={0.f,0.f,0.f,0.f}, a1={0.f,0.f,0.f,0.f}, a2={0.f,0.f,0.f,0.f};

                // ---- w_z · x (K=256, pre-spin, hf1) ----
                if (hf == 1) {
                    const float* xp = x + ((size_t)u*128 + bb)*256;
                    #pragma unroll 2
                    for (int i = 0; i < 8; ++i) {
                        short8 xhi, xlo; cvt8_hilo(xp + i*32 + ko8, xhi, xlo);
                        short8 whi = *(const short8*)(lds_us + J_WZ_HI + r16*264 + i*32 + ko8);
                        short8 wlo = *(const short8*)(lds_us + J_WZ_LO + r16*264 + i*32 + ko8);
                        a0 = MFMA16(whi, xhi, a0);
                        a1 = MFMA16(whi, xlo, a1);
                        a2 = MFMA16(wlo, xhi, a2);
                    }
                }

                if (coop) {
                    if (tid == 0) {
                        spin_ge(&d_mgrp[bh][0][u], 16);
                        spin_ge(&d_mgrp[bh][1][u], 16);
                        spin_ge(&d_mgrp[bh][2][u], 16);
                        spin_ge(&d_mgrp[bh][3][u], 16);
                        if (u >= 1) spin_ge(&d_jflag[bh][u-1], 64);
                    }
                    __syncthreads();
                }

                // ---- K=1024: u_c·ng(u) (hf0) or u_z·hj(u-1) (hf1) ----
                {
                    const int aHI = (hf ? (HJ_HI + p1*131072) : (NG_HI + p0*131072)) + bb*1024;
                    const int aLO = (hf ? (HJ_LO + p1*131072) : (NG_LO + p0*131072)) + bb*1024;
                    const int wHI = (hf ? J_UZ_HI : J_UC_HI) + r16*1032;
                    const int wLO = (hf ? J_UZ_LO : J_UC_LO) + r16*1032;
                    #pragma unroll 4
                    for (int i = 0; i < 32; ++i) {
                        short8 ahi = ald16(U + aHI + i*32 + ko8);
                        short8 alo = ald16(U + aLO + i*32 + ko8);
                        short8 whi = *(const short8*)(lds_us + wHI + i*32 + ko8);
                        short8 wlo = *(const short8*)(lds_us + wLO + i*32 + ko8);
                        a0 = MFMA16(whi, ahi, a0);
                        a1 = MFMA16(whi, alo, a1);
                        a2 = MFMA16(wlo, ahi, a2);
                    }
                }
                f32x4 acc = a0 + a1 + a2;

                if (hf == 1) {
                    #pragma unroll
                    for (int r = 0; r < 4; ++r) {
                        int idx = (q4 + r)*16 + r16;
                        exch[tb*256 + idx] = acc[r];            // zj partial
                    }
                }
                __syncthreads();
                if (hf == 0) {
                    const int jb  = j0 + q4;
                    const int o1  = p1*131072 + bb*1024 + jb;
                    const int o0  = p0*131072 + bb*1024 + jb;
                    us4 hhi = ald8v(U + HJ_HI + o1);
                    us4 hlo = ald8v(U + HJ_LO + o1);
                    us4 hjhi, hjlo;
                    float hv[4];
                    #pragma unroll
                    for (int r = 0; r < 4; ++r) {
                        int idx = (q4 + r)*16 + r16;
                        float zacc = exch[tb*256 + idx];
                        float cg_  = tanhfast(acc[r] + bc_[r]);
                        float zj   = sigf(zacc + bzj_[r]);
                        float hjo  = bf2f(hhi[r]) + bf2f(hlo[r]);
                        float hnew = cg_ + zj * (hjo - cg_);
                        unsigned short h1 = f2bf(hnew);
                        hjhi[r] = h1; hjlo[r] = f2bf(hnew - bf2f(h1));
                        hv[r] = hnew;
                    }
                    ast8(U + HJ_HI + o0, hjhi);
                    ast8(U + HJ_LO + o0, hjlo);
                    if (u == Tn-1) {
                        float4 o; o.x=hv[0]; o.y=hv[1]; o.z=hv[2]; o.w=hv[3];
                        *(float4*)(out + (size_t)bb*1024 + jb) = o;
                    }
                }
                __syncthreads();   // drains vmcnt: scoped stores complete at L3
                if (coop && tid == 0) {
                    atomicAdd(&d_jflag[bh][u], 1);
                }
            }
        }
    }
}

extern "C" void kernel_launch(void* const* d_in, const int* in_sizes, int n_in,
                              void* d_out, int out_size, void* d_ws, size_t ws_size,
                              hipStream_t stream) {
    const float* x    = (const float*)d_in[0];
    const float* w_ih = (const float*)d_in[1];
    const float* w_hh = (const float*)d_in[2];
    const float* b_ih = (const float*)d_in[3];
    const float* u_c  = (const float*)d_in[4];
    const float* b_c  = (const float*)d_in[5];
    const float* w_z  = (const float*)d_in[6];
    const float* u_z  = (const float*)d_in[7];
    const float* b_z  = (const float*)d_in[8];
    float* out = (float*)d_out;
    float* ws  = (float*)d_ws;

    (void)hipFuncSetAttribute((const void*)mgrn_k,
                              hipFuncAttributeMaxDynamicSharedMemorySize,
                              LDS_BYTES);

    // Residency guard: only the cooperative path if the whole grid fits.
    int maxb = 0;
    hipError_t qe = hipOccupancyMaxActiveBlocksPerMultiprocessor(
                        &maxb, (const void*)mgrn_k, NTHR, (size_t)LDS_BYTES);
    bool can_coop = (qe == hipSuccess) && (maxb * 256 >= NBLK);

    int s_lo = 0, s_hi = Tn, coop = 1;
    void* args[] = {&x, &w_ih, &w_hh, &b_ih, &u_c, &b_c, &w_z, &u_z, &b_z,
                    &out, &ws, &s_lo, &s_hi, &coop};
    hipError_t e = hipErrorUnknown;
    if (can_coop)
        e = hipLaunchCooperativeKernel((void*)mgrn_k, dim3(NBLK), dim3(NTHR),
                                       args, LDS_BYTES, stream);
    if (e != hipSuccess) {
        (void)hipGetLastError();   // clear sticky error
        hipMemsetAsync(ws, 0, (size_t)786432 * sizeof(float), stream);
        for (int s = 0; s <= Tn; ++s) {
            mgrn_k<<<dim3(NBLK), dim3(NTHR), LDS_BYTES, stream>>>(
                x, w_ih, w_hh, b_ih, u_c, b_c, w_z, u_z, b_z, out, ws, s, s, 0);
        }
    }
}

// Round 17
// 16085.316 us; speedup vs baseline: 1.0514x; 1.0514x over previous
//
#include <hip/hip_runtime.h>
#include <hip/hip_cooperative_groups.h>

namespace cg = cooperative_groups;

typedef short short8 __attribute__((ext_vector_type(8)));
typedef float f32x4  __attribute__((ext_vector_type(4)));
typedef unsigned short us4 __attribute__((ext_vector_type(4)));
typedef unsigned long long u64t;

#define Tn 512
#define NBLK 256
#define NTHR 512

#define MFMA16(A,B,C) __builtin_amdgcn_mfma_f32_16x16x32_bf16(A,B,C,0,0,0)

// ---- LDS layout (ushort units) ----
#define J_UC_HI 0
#define J_UC_LO 16512
#define J_UZ_HI 33024
#define J_UZ_LO 49536
#define J_WZ_HI 66048
#define J_WZ_LO 70272
#define J_EX_US 74496          // float exch here (1024 floats)
#define M_WIH_HI 0
#define M_WIH_LO 3456
#define M_WHH_HI 6912
#define M_WHH_LO 19584
#define M_EX_US 32256          // float exch here (2048 floats)
#define LDS_BYTES 153088

// ---- ws planes (ushort units); each plane 131072, buf p at +p*131072 ----
#define HM_HI 0
#define HM_LO 262144
#define NG_HI 524288
#define NG_LO 786432
#define HJ_HI 1048576
#define HJ_LO 1310720

__device__ __forceinline__ float sigf(float v){ return 1.0f/(1.0f+__expf(-v)); }
__device__ __forceinline__ float tanhfast(float v){
    float ax=fabsf(v); float e=__expf(-2.0f*ax);
    float t=(1.0f-e)/(1.0f+e); return copysignf(t,v);
}
__device__ __forceinline__ unsigned short f2bf(float f){
    union{float f; unsigned u;} v; v.f=f;
    unsigned r = v.u + 0x7FFFu + ((v.u>>16)&1u);
    return (unsigned short)(r>>16);
}
__device__ __forceinline__ float bf2f(unsigned short h){
    union{unsigned u; float f;} w; w.u = ((unsigned)h)<<16; return w.f;
}
__device__ __forceinline__ void cvt8_hilo(const float* p, short8& hi, short8& lo){
    float4 a = *(const float4*)p;
    float4 b = *(const float4*)(p+4);
    float v[8] = {a.x,a.y,a.z,a.w,b.x,b.y,b.z,b.w};
    #pragma unroll
    for (int e = 0; e < 8; ++e) {
        unsigned short h = f2bf(v[e]);
        hi[e] = (short)h;
        lo[e] = (short)f2bf(v[e] - bf2f(h));
    }
}

// ---- agent-scoped (device-coherent, L2-bypassing) state access ----
__device__ __forceinline__ short8 ald16(const unsigned short* p){
    u64t a = __hip_atomic_load((const u64t*)p,     __ATOMIC_RELAXED, __HIP_MEMORY_SCOPE_AGENT);
    u64t b = __hip_atomic_load((const u64t*)(p+4), __ATOMIC_RELAXED, __HIP_MEMORY_SCOPE_AGENT);
    union { u64t q[2]; short8 s; } u;
    u.q[0]=a; u.q[1]=b; return u.s;
}
__device__ __forceinline__ us4 ald8v(const unsigned short* p){
    u64t a = __hip_atomic_load((const u64t*)p, __ATOMIC_RELAXED, __HIP_MEMORY_SCOPE_AGENT);
    union { u64t q; us4 v; } u; u.q=a; return u.v;
}
__device__ __forceinline__ void ast8(unsigned short* p, us4 v){
    union { us4 v; u64t q; } u; u.v=v;
    __hip_atomic_store((u64t*)p, u.q, __ATOMIC_RELAXED, __HIP_MEMORY_SCOPE_AGENT);
}

// ---- sync: producer counts (RMW line) + single-writer ready flags (poll line)
__device__ int d_mcnt[2][4][513];   // marg producers increment; last (old==15) sets rdy
__device__ int d_mrdy[2][4][513];
__device__ int d_jcnt[2][513];      // joint producers increment; last (old==63) sets rdy
__device__ int d_jrdy[2][513];

__device__ __forceinline__ void spin1(const int* p){
    while (__hip_atomic_load(p, __ATOMIC_RELAXED, __HIP_MEMORY_SCOPE_AGENT) == 0)
        __builtin_amdgcn_s_sleep(1);
}

__launch_bounds__(NTHR, 1)
__global__ void mgrn_k(const float* __restrict__ x,
                       const float* __restrict__ w_ih,
                       const float* __restrict__ w_hh,
                       const float* __restrict__ b_ih,
                       const float* __restrict__ u_c,
                       const float* __restrict__ b_c,
                       const float* __restrict__ w_z,
                       const float* __restrict__ u_z,
                       const float* __restrict__ b_z,
                       float* __restrict__ out,
                       float* __restrict__ ws,
                       int s_lo, int s_hi, int coop)
{
    cg::grid_group grid = cg::this_grid();
    extern __shared__ unsigned short lds_us[];

    unsigned short* U = (unsigned short*)ws;
    unsigned int*  U32 = (unsigned int*)ws;

    const int tid  = threadIdx.x;
    const int lane = tid & 63;
    const int wv   = tid >> 6;          // 0..7
    const int tb   = wv & 3;            // b-tile 0..3
    const int hf   = wv >> 2;           // role half
    const int r16  = lane & 15;
    const int q4   = (lane >> 4) * 4;
    const int ko8  = (lane >> 4) * 8;   // k-chunk (shorts)
    const int wg   = blockIdx.x;
    const bool isMarg = (wg < 128);

    if (coop) {   // zero t=-1 (buf 1) hi/lo planes of hm,hj + flags
        int gidx = wg * NTHR + tid;     // [0, 131072)
        if (gidx < 65536) {
            U32[ 65536 + gidx] = 0u;    // HM_HI buf1
            U32[196608 + gidx] = 0u;    // HM_LO buf1
            U32[589824 + gidx] = 0u;    // HJ_HI buf1
            U32[720896 + gidx] = 0u;    // HJ_LO buf1
        }
        int* p1 = &d_mcnt[0][0][0]; if (gidx < 4104) p1[gidx] = 0;
        int* p2 = &d_mrdy[0][0][0]; if (gidx < 4104) p2[gidx] = 0;
        int* p3 = &d_jcnt[0][0];    if (gidx < 1026) p3[gidx] = 0;
        int* p4 = &d_jrdy[0][0];    if (gidx < 1026) p4[gidx] = 0;
    }

    if (isMarg) {
        // ============ MARGINAL: block = 16 h-rows x 64 batch ============
        const int c  = wg >> 1;
        const int bh = wg & 1;
        const int g  = c >> 4;
        const int h0 = (c & 15) * 16;
        const int bb = bh*64 + tb*16 + r16;   // this lane's batch

        const float* wih_g = w_ih + (size_t)g * 768 * 64;
        const float* whh_g = w_hh + (size_t)g * 768 * 256;
        float* exch = (float*)(lds_us + M_EX_US);

        // ---- stage weights to LDS as hi/lo (rows: gate*16 + (h-h0)) ----
        for (int i = tid; i < 48*64; i += NTHR) {
            int r = i >> 6, k = i & 63;
            int gate = r >> 4, row = r & 15;
            float v = wih_g[(size_t)(gate*256 + h0 + row)*64 + k];
            unsigned short h = f2bf(v);
            lds_us[M_WIH_HI + r*72 + k] = h;
            lds_us[M_WIH_LO + r*72 + k] = f2bf(v - bf2f(h));
        }
        for (int i = tid; i < 48*256; i += NTHR) {
            int r = i >> 8, k = i & 255;
            int gate = r >> 4, row = r & 15;
            float v = whh_g[(size_t)(gate*256 + h0 + row)*256 + k];
            unsigned short h = f2bf(v);
            lds_us[M_WHH_HI + r*264 + k] = h;
            lds_us[M_WHH_LO + r*264 + k] = f2bf(v - bf2f(h));
        }
        __syncthreads();
        if (coop) { grid.sync(); __threadfence(); }   // one-time: init visibility

        const int rAw = hf ? 16 : 0;          // accA gate rows (r / z)

        float br_[4], bz_[4], bn_[4];
        #pragma unroll
        for (int r = 0; r < 4; ++r) {
            int hh = h0 + q4 + r;
            br_[r] = b_ih[g*768 + hh];
            bz_[r] = b_ih[g*768 + 256 + hh];
            bn_[r] = b_ih[g*768 + 512 + hh];
        }

        for (int s = s_lo; s <= s_hi; ++s) {
            if (s < Tn) {
                const int p0 = s & 1, p1 = (s+1) & 1;
                f32x4 aA0={0.f,0.f,0.f,0.f}, aA1={0.f,0.f,0.f,0.f}, aA2={0.f,0.f,0.f,0.f};
                f32x4 aB0={0.f,0.f,0.f,0.f}, aB1={0.f,0.f,0.f,0.f}, aB2={0.f,0.f,0.f,0.f};
                const float* xp = x + ((size_t)s*128 + bb)*256 + g*64;

                // ---- x-part (K=64, pre-spin) ----
                #pragma unroll
                for (int i = 0; i < 2; ++i) {
                    short8 xhi, xlo; cvt8_hilo(xp + i*32 + ko8, xhi, xlo);
                    short8 whi = *(const short8*)(lds_us + M_WIH_HI + (rAw + r16)*72 + i*32 + ko8);
                    short8 wlo = *(const short8*)(lds_us + M_WIH_LO + (rAw + r16)*72 + i*32 + ko8);
                    aA0 = MFMA16(whi, xhi, aA0);
                    aA1 = MFMA16(whi, xlo, aA1);
                    aA2 = MFMA16(wlo, xhi, aA2);
                    if (hf == 0) {
                        short8 nhi = *(const short8*)(lds_us + M_WIH_HI + (32 + r16)*72 + i*32 + ko8);
                        short8 nlo = *(const short8*)(lds_us + M_WIH_LO + (32 + r16)*72 + i*32 + ko8);
                        aB0 = MFMA16(nhi, xhi, aB0);
                        aB1 = MFMA16(nhi, xlo, aB1);
                        aB2 = MFMA16(nlo, xhi, aB2);
                    }
                }

                if (coop) {
                    if (tid == 0 && s >= 1) spin1(&d_mrdy[bh][g][s-1]);
                    if (tid == 1 && s >= 2) spin1(&d_jrdy[bh][s-2]);
                    __syncthreads();
                }

                // epilogue-state prefetch (hf0 only): issue early, use later
                const int kkb = g*256 + h0 + q4;
                const int o1  = p1*131072 + bb*1024 + kkb;
                us4 pf_hhi{}, pf_hlo{};
                if (hf == 0) { pf_hhi = ald8v(U + HM_HI + o1); pf_hlo = ald8v(U + HM_LO + o1); }

                // ---- h-part (K=256), agent-scoped state loads ----
                {
                    const int hofs = p1*131072 + bb*1024 + g*256;
                    #pragma unroll 2
                    for (int i = 0; i < 8; ++i) {
                        short8 hhi = ald16(U + HM_HI + hofs + i*32 + ko8);
                        short8 hlo = ald16(U + HM_LO + hofs + i*32 + ko8);
                        short8 whi = *(const short8*)(lds_us + M_WHH_HI + (rAw + r16)*264 + i*32 + ko8);
                        short8 wlo = *(const short8*)(lds_us + M_WHH_LO + (rAw + r16)*264 + i*32 + ko8);
                        aA0 = MFMA16(whi, hhi, aA0);
                        aA1 = MFMA16(whi, hlo, aA1);
                        aA2 = MFMA16(wlo, hhi, aA2);
                        if (hf == 1) {
                            short8 nhi = *(const short8*)(lds_us + M_WHH_HI + (32 + r16)*264 + i*32 + ko8);
                            short8 nlo = *(const short8*)(lds_us + M_WHH_LO + (32 + r16)*264 + i*32 + ko8);
                            aB0 = MFMA16(nhi, hhi, aB0);
                            aB1 = MFMA16(nhi, hlo, aB1);
                            aB2 = MFMA16(nlo, hhi, aB2);
                        }
                    }
                }
                f32x4 accA = aA0 + aA1 + aA2;
                f32x4 accB = aB0 + aB1 + aB2;

                if (hf == 1) {
                    #pragma unroll
                    for (int r = 0; r < 4; ++r) {
                        int idx = (q4 + r)*16 + r16;
                        exch[(tb*2 + 0)*256 + idx] = accA[r];   // z partial
                        exch[(tb*2 + 1)*256 + idx] = accB[r];   // hn partial
                    }
                }
                __syncthreads();
                if (hf == 0) {
                    const int o0 = p0*131072 + bb*1024 + kkb;
                    us4 hmhi, hmlo, nghi, nglo;
                    #pragma unroll
                    for (int r = 0; r < 4; ++r) {
                        int idx = (q4 + r)*16 + r16;
                        float zacc  = exch[(tb*2 + 0)*256 + idx];
                        float hnacc = exch[(tb*2 + 1)*256 + idx];
                        float rg = sigf(accA[r] + br_[r]);
                        float zg = sigf(zacc + bz_[r]);
                        float n  = tanhfast(accB[r] + bn_[r] + rg * hnacc);
                        float hmo = bf2f(pf_hhi[r]) + bf2f(pf_hlo[r]);
                        float hnew = n + zg * (hmo - n);
                        unsigned short h1 = f2bf(hnew);
                        hmhi[r] = h1; hmlo[r] = f2bf(hnew - bf2f(h1));
                        unsigned short h2 = f2bf(n);
                        nghi[r] = h2; nglo[r] = f2bf(n - bf2f(h2));
                    }
                    ast8(U + HM_HI + o0, hmhi);
                    ast8(U + HM_LO + o0, hmlo);
                    ast8(U + NG_HI + o0, nghi);
                    ast8(U + NG_LO + o0, nglo);
                }
                __syncthreads();   // drains vmcnt: scoped stores complete at L3
                if (coop && tid == 0) {
                    int old = atomicAdd(&d_mcnt[bh][g][s], 1);
                    if (old == 15)
                        __hip_atomic_store(&d_mrdy[bh][g][s], 1,
                                           __ATOMIC_RELAXED, __HIP_MEMORY_SCOPE_AGENT);
                }
            }
        }
    } else {
        // ============ JOINT: block = 16 j-rows x 64 batch, 1 step behind ====
        const int wg2 = wg - 128;
        const int j0  = (wg2 >> 1) * 16;
        const int bh  = wg2 & 1;
        const int bb  = bh*64 + tb*16 + r16;
        float* exch = (float*)(lds_us + J_EX_US);

        // ---- stage weights to LDS as hi/lo ----
        for (int i = tid; i < 16*1024; i += NTHR) {
            int r = i >> 10, k = i & 1023;
            float v = u_c[(size_t)(j0 + r)*1024 + k];
            unsigned short h = f2bf(v);
            lds_us[J_UC_HI + r*1032 + k] = h;
            lds_us[J_UC_LO + r*1032 + k] = f2bf(v - bf2f(h));
            v = u_z[(size_t)(j0 + r)*1024 + k];
            h = f2bf(v);
            lds_us[J_UZ_HI + r*1032 + k] = h;
            lds_us[J_UZ_LO + r*1032 + k] = f2bf(v - bf2f(h));
        }
        for (int i = tid; i < 16*256; i += NTHR) {
            int r = i >> 8, k = i & 255;
            float v = w_z[(size_t)(j0 + r)*256 + k];
            unsigned short h = f2bf(v);
            lds_us[J_WZ_HI + r*264 + k] = h;
            lds_us[J_WZ_LO + r*264 + k] = f2bf(v - bf2f(h));
        }
        __syncthreads();
        if (coop) { grid.sync(); __threadfence(); }   // one-time: init visibility

        float bc_[4], bzj_[4];
        #pragma unroll
        for (int r = 0; r < 4; ++r) {
            int jj = j0 + q4 + r;
            bc_[r]  = b_c[jj];
            bzj_[r] = b_z[jj];
        }

        for (int s = s_lo; s <= s_hi; ++s) {
            if (s >= 1) {
                const int u  = s - 1;
                const int p0 = u & 1, p1 = (u+1) & 1;
                f32x4 a0={0.f,0.f,0.f,0.f}, a1={0.f,0.f,0.f,0.f}, a2={0.f,0.f,0.f,0.f};

                // ---- w_z · x (K=256, pre-spin, hf1) ----
                if (hf == 1) {
                    const float* xp = x + ((size_t)u*128 + bb)*256;
                    #pragma unroll 2
                    for (int i = 0; i < 8; ++i) {
                        short8 xhi, xlo; cvt8_hilo(xp + i*32 + ko8, xhi, xlo);
                        short8 whi = *(const short8*)(lds_us + J_WZ_HI + r16*264 + i*32 + ko8);
                        short8 wlo = *(const short8*)(lds_us + J_WZ_LO + r16*264 + i*32 + ko8);
                        a0 = MFMA16(whi, xhi, a0);
                        a1 = MFMA16(whi, xlo, a1);
                        a2 = MFMA16(wlo, xhi, a2);
                    }
                }

                if (coop) {
                    if (tid < 4) spin1(&d_mrdy[bh][tid][u]);      // lane-parallel
                    if (tid == 4 && u >= 1) spin1(&d_jrdy[bh][u-1]);
                    __syncthreads();
                }

                // epilogue-state prefetch (hf0 only)
                const int jb = j0 + q4;
                const int o1 = p1*131072 + bb*1024 + jb;
                us4 pf_hhi{}, pf_hlo{};
                if (hf == 0) { pf_hhi = ald8v(U + HJ_HI + o1); pf_hlo = ald8v(U + HJ_LO + o1); }

                // ---- K=1024: u_c·ng(u) (hf0) or u_z·hj(u-1) (hf1) ----
                {
                    const int aHI = (hf ? (HJ_HI + p1*131072) : (NG_HI + p0*131072)) + bb*1024;
                    const int aLO = (hf ? (HJ_LO + p1*131072) : (NG_LO + p0*131072)) + bb*1024;
                    const int wHI = (hf ? J_UZ_HI : J_UC_HI) + r16*1032;
                    const int wLO = (hf ? J_UZ_LO : J_UC_LO) + r16*1032;
                    #pragma unroll 4
                    for (int i = 0; i < 32; ++i) {
                        short8 ahi = ald16(U + aHI + i*32 + ko8);
                        short8 alo = ald16(U + aLO + i*32 + ko8);
                        short8 whi = *(const short8*)(lds_us + wHI + i*32 + ko8);
                        short8 wlo = *(const short8*)(lds_us + wLO + i*32 + ko8);
                        a0 = MFMA16(whi, ahi, a0);
                        a1 = MFMA16(whi, alo, a1);
                        a2 = MFMA16(wlo, ahi, a2);
                    }
                }
                f32x4 acc = a0 + a1 + a2;

                if (hf == 1) {
                    #pragma unroll
                    for (int r = 0; r < 4; ++r) {
                        int idx = (q4 + r)*16 + r16;
                        exch[tb*256 + idx] = acc[r];            // zj partial
                    }
                }
                __syncthreads();
                if (hf == 0) {
                    const int o0 = p0*131072 + bb*1024 + jb;
                    us4 hjhi, hjlo;
                    float hv[4];
                    #pragma unroll
                    for (int r = 0; r < 4; ++r) {
                        int idx = (q4 + r)*16 + r16;
                        float zacc = exch[tb*256 + idx];
                        float cg_  = tanhfast(acc[r] + bc_[r]);
                        float zj   = sigf(zacc + bzj_[r]);
                        float hjo  = bf2f(pf_hhi[r]) + bf2f(pf_hlo[r]);
                        float hnew = cg_ + zj * (hjo - cg_);
                        unsigned short h1 = f2bf(hnew);
                        hjhi[r] = h1; hjlo[r] = f2bf(hnew - bf2f(h1));
                        hv[r] = hnew;
                    }
                    ast8(U + HJ_HI + o0, hjhi);
                    ast8(U + HJ_LO + o0, hjlo);
                    if (u == Tn-1) {
                        float4 o; o.x=hv[0]; o.y=hv[1]; o.z=hv[2]; o.w=hv[3];
                        *(float4*)(out + (size_t)bb*1024 + jb) = o;
                    }
                }
                __syncthreads();   // drains vmcnt: scoped stores complete at L3
                if (coop && tid == 0) {
                    int old = atomicAdd(&d_jcnt[bh][u], 1);
                    if (old == 63)
                        __hip_atomic_store(&d_jrdy[bh][u], 1,
                                           __ATOMIC_RELAXED, __HIP_MEMORY_SCOPE_AGENT);
                }
            }
        }
    }
}

extern "C" void kernel_launch(void* const* d_in, const int* in_sizes, int n_in,
                              void* d_out, int out_size, void* d_ws, size_t ws_size,
                              hipStream_t stream) {
    const float* x    = (const float*)d_in[0];
    const float* w_ih = (const float*)d_in[1];
    const float* w_hh = (const float*)d_in[2];
    const float* b_ih = (const float*)d_in[3];
    const float* u_c  = (const float*)d_in[4];
    const float* b_c  = (const float*)d_in[5];
    const float* w_z  = (const float*)d_in[6];
    const float* u_z  = (const float*)d_in[7];
    const float* b_z  = (const float*)d_in[8];
    float* out = (float*)d_out;
    float* ws  = (float*)d_ws;

    (void)hipFuncSetAttribute((const void*)mgrn_k,
                              hipFuncAttributeMaxDynamicSharedMemorySize,
                              LDS_BYTES);

    // Residency guard: only the cooperative path if the whole grid fits.
    int maxb = 0;
    hipError_t qe = hipOccupancyMaxActiveBlocksPerMultiprocessor(
                        &maxb, (const void*)mgrn_k, NTHR, (size_t)LDS_BYTES);
    bool can_coop = (qe == hipSuccess) && (maxb * 256 >= NBLK);

    int s_lo = 0, s_hi = Tn, coop = 1;
    void* args[] = {&x, &w_ih, &w_hh, &b_ih, &u_c, &b_c, &w_z, &u_z, &b_z,
                    &out, &ws, &s_lo, &s_hi, &coop};
    hipError_t e = hipErrorUnknown;
    if (can_coop)
        e = hipLaunchCooperativeKernel((void*)mgrn_k, dim3(NBLK), dim3(NTHR),
                                       args, LDS_BYTES, stream);
    if (e != hipSuccess) {
        (void)hipGetLastError();   // clear sticky error
        hipMemsetAsync(ws, 0, (size_t)786432 * sizeof(float), stream);
        for (int s = 0; s <= Tn; ++s) {
            mgrn_k<<<dim3(NBLK), dim3(NTHR), LDS_BYTES, stream>>>(
                x, w_ih, w_hh, b_ih, u_c, b_c, w_z, u_z, b_z, out, ws, s, s, 0);
        }
    }
}

// Round 18
// 9094.828 us; speedup vs baseline: 1.8595x; 1.7686x over previous
//
#include <hip/hip_runtime.h>
#include <hip/hip_cooperative_groups.h>

namespace cg = cooperative_groups;

typedef short short8 __attribute__((ext_vector_type(8)));
typedef float f32x4  __attribute__((ext_vector_type(4)));
typedef unsigned short us4 __attribute__((ext_vector_type(4)));
typedef unsigned long long u64t;

#define Tn 512
#define NBLK 256
#define NTHR 512

#define MFMA16(A,B,C) __builtin_amdgcn_mfma_f32_16x16x32_bf16(A,B,C,0,0,0)

// ---- LDS layout (ushort units) ----
#define J_UC_HI 0
#define J_UC_LO 16512
#define J_UZ_HI 33024
#define J_UZ_LO 49536
#define J_WZ_HI 66048
#define J_WZ_LO 70272
#define J_EX_US 74496          // float exch here (1024 floats)
#define M_WIH_HI 0
#define M_WIH_LO 3456
#define M_WHH_HI 6912
#define M_WHH_LO 19584
#define M_EX_US 32256          // float exch here (2048 floats)
#define LDS_BYTES 153088

// ---- ws planes (ushort units); each plane 131072, buf p at +p*131072 ----
#define HM_HI 0
#define HM_LO 262144
#define NG_HI 524288
#define NG_LO 786432
#define HJ_HI 1048576
#define HJ_LO 1310720

__device__ __forceinline__ float sigf(float v){ return 1.0f/(1.0f+__expf(-v)); }
__device__ __forceinline__ float tanhfast(float v){
    float ax=fabsf(v); float e=__expf(-2.0f*ax);
    float t=(1.0f-e)/(1.0f+e); return copysignf(t,v);
}
__device__ __forceinline__ unsigned short f2bf(float f){
    union{float f; unsigned u;} v; v.f=f;
    unsigned r = v.u + 0x7FFFu + ((v.u>>16)&1u);
    return (unsigned short)(r>>16);
}
__device__ __forceinline__ float bf2f(unsigned short h){
    union{unsigned u; float f;} w; w.u = ((unsigned)h)<<16; return w.f;
}
__device__ __forceinline__ void cvt8_hilo(const float* p, short8& hi, short8& lo){
    float4 a = *(const float4*)p;
    float4 b = *(const float4*)(p+4);
    float v[8] = {a.x,a.y,a.z,a.w,b.x,b.y,b.z,b.w};
    #pragma unroll
    for (int e = 0; e < 8; ++e) {
        unsigned short h = f2bf(v[e]);
        hi[e] = (short)h;
        lo[e] = (short)f2bf(v[e] - bf2f(h));
    }
}

// ---- agent-scoped (device-coherent, L2-bypassing) state access ----
__device__ __forceinline__ short8 ald16(const unsigned short* p){
    u64t a = __hip_atomic_load((const u64t*)p,     __ATOMIC_RELAXED, __HIP_MEMORY_SCOPE_AGENT);
    u64t b = __hip_atomic_load((const u64t*)(p+4), __ATOMIC_RELAXED, __HIP_MEMORY_SCOPE_AGENT);
    union { u64t q[2]; short8 s; } u;
    u.q[0]=a; u.q[1]=b; return u.s;
}
__device__ __forceinline__ us4 ald8v(const unsigned short* p){
    u64t a = __hip_atomic_load((const u64t*)p, __ATOMIC_RELAXED, __HIP_MEMORY_SCOPE_AGENT);
    union { u64t q; us4 v; } u; u.q=a; return u.v;
}
__device__ __forceinline__ void ast8(unsigned short* p, us4 v){
    union { us4 v; u64t q; } u; u.v=v;
    __hip_atomic_store((u64t*)p, u.q, __ATOMIC_RELAXED, __HIP_MEMORY_SCOPE_AGENT);
}

// ---- sync: producer counts (RMW line) + single-writer ready flags (poll line)
__device__ int d_mcnt[2][4][513];   // marg producers increment; last (old==15) sets rdy
__device__ int d_mrdy[2][4][513];
__device__ int d_jcnt[2][513];      // joint producers increment; last (old==63) sets rdy
__device__ int d_jrdy[2][513];

__device__ __forceinline__ void spin1(const int* p){
    while (__hip_atomic_load(p, __ATOMIC_RELAXED, __HIP_MEMORY_SCOPE_AGENT) == 0)
        __builtin_amdgcn_s_sleep(1);
}

__launch_bounds__(NTHR, 1)
__global__ void mgrn_k(const float* __restrict__ x,
                       const float* __restrict__ w_ih,
                       const float* __restrict__ w_hh,
                       const float* __restrict__ b_ih,
                       const float* __restrict__ u_c,
                       const float* __restrict__ b_c,
                       const float* __restrict__ w_z,
                       const float* __restrict__ u_z,
                       const float* __restrict__ b_z,
                       float* __restrict__ out,
                       float* __restrict__ ws,
                       int s_lo, int s_hi, int coop)
{
    cg::grid_group grid = cg::this_grid();
    extern __shared__ unsigned short lds_us[];

    unsigned short* U = (unsigned short*)ws;
    unsigned int*  U32 = (unsigned int*)ws;

    const int tid  = threadIdx.x;
    const int lane = tid & 63;
    const int wv   = tid >> 6;          // 0..7
    const int tb   = wv & 3;            // b-tile 0..3
    const int hf   = wv >> 2;           // role half
    const int r16  = lane & 15;
    const int q4   = (lane >> 4) * 4;
    const int ko8  = (lane >> 4) * 8;   // k-chunk (shorts)
    const int wg   = blockIdx.x;
    const bool isMarg = (wg < 128);

    if (coop) {   // zero t=-1 (buf 1) hi/lo planes of hm,hj + flags
        int gidx = wg * NTHR + tid;     // [0, 131072)
        if (gidx < 65536) {
            U32[ 65536 + gidx] = 0u;    // HM_HI buf1
            U32[196608 + gidx] = 0u;    // HM_LO buf1
            U32[589824 + gidx] = 0u;    // HJ_HI buf1
            U32[720896 + gidx] = 0u;    // HJ_LO buf1
        }
        int* p1 = &d_mcnt[0][0][0]; if (gidx < 4104) p1[gidx] = 0;
        int* p2 = &d_mrdy[0][0][0]; if (gidx < 4104) p2[gidx] = 0;
        int* p3 = &d_jcnt[0][0];    if (gidx < 1026) p3[gidx] = 0;
        int* p4 = &d_jrdy[0][0];    if (gidx < 1026) p4[gidx] = 0;
    }

    if (isMarg) {
        // ============ MARGINAL: block = 16 h-rows x 64 batch ============
        const int c  = wg >> 1;
        const int bh = wg & 1;
        const int g  = c >> 4;
        const int h0 = (c & 15) * 16;
        const int bb = bh*64 + tb*16 + r16;   // this lane's batch

        const float* wih_g = w_ih + (size_t)g * 768 * 64;
        const float* whh_g = w_hh + (size_t)g * 768 * 256;
        float* exch = (float*)(lds_us + M_EX_US);

        // ---- stage weights to LDS as hi/lo (rows: gate*16 + (h-h0)) ----
        for (int i = tid; i < 48*64; i += NTHR) {
            int r = i >> 6, k = i & 63;
            int gate = r >> 4, row = r & 15;
            float v = wih_g[(size_t)(gate*256 + h0 + row)*64 + k];
            unsigned short h = f2bf(v);
            lds_us[M_WIH_HI + r*72 + k] = h;
            lds_us[M_WIH_LO + r*72 + k] = f2bf(v - bf2f(h));
        }
        for (int i = tid; i < 48*256; i += NTHR) {
            int r = i >> 8, k = i & 255;
            int gate = r >> 4, row = r & 15;
            float v = whh_g[(size_t)(gate*256 + h0 + row)*256 + k];
            unsigned short h = f2bf(v);
            lds_us[M_WHH_HI + r*264 + k] = h;
            lds_us[M_WHH_LO + r*264 + k] = f2bf(v - bf2f(h));
        }
        __syncthreads();
        if (coop) { grid.sync(); __threadfence(); }   // one-time: init visibility

        const int rAw = hf ? 16 : 0;          // accA gate rows (r / z)

        float br_[4], bz_[4], bn_[4];
        #pragma unroll
        for (int r = 0; r < 4; ++r) {
            int hh = h0 + q4 + r;
            br_[r] = b_ih[g*768 + hh];
            bz_[r] = b_ih[g*768 + 256 + hh];
            bn_[r] = b_ih[g*768 + 512 + hh];
        }

        for (int s = s_lo; s <= s_hi; ++s) {
            if (s < Tn) {
                const int p0 = s & 1, p1 = (s+1) & 1;
                f32x4 aA0={0.f,0.f,0.f,0.f}, aA1={0.f,0.f,0.f,0.f}, aA2={0.f,0.f,0.f,0.f};
                f32x4 aB0={0.f,0.f,0.f,0.f}, aB1={0.f,0.f,0.f,0.f}, aB2={0.f,0.f,0.f,0.f};
                const float* xp = x + ((size_t)s*128 + bb)*256 + g*64;

                // ---- x-part (K=64, pre-spin) ----
                #pragma unroll
                for (int i = 0; i < 2; ++i) {
                    short8 xhi, xlo; cvt8_hilo(xp + i*32 + ko8, xhi, xlo);
                    short8 whi = *(const short8*)(lds_us + M_WIH_HI + (rAw + r16)*72 + i*32 + ko8);
                    short8 wlo = *(const short8*)(lds_us + M_WIH_LO + (rAw + r16)*72 + i*32 + ko8);
                    aA0 = MFMA16(whi, xhi, aA0);
                    aA1 = MFMA16(whi, xlo, aA1);
                    aA2 = MFMA16(wlo, xhi, aA2);
                    if (hf == 0) {
                        short8 nhi = *(const short8*)(lds_us + M_WIH_HI + (32 + r16)*72 + i*32 + ko8);
                        short8 nlo = *(const short8*)(lds_us + M_WIH_LO + (32 + r16)*72 + i*32 + ko8);
                        aB0 = MFMA16(nhi, xhi, aB0);
                        aB1 = MFMA16(nhi, xlo, aB1);
                        aB2 = MFMA16(nlo, xhi, aB2);
                    }
                }

                if (coop) {
                    if (tid == 0 && s >= 1) spin1(&d_mrdy[bh][g][s-1]);
                    if (tid == 1 && s >= 2) spin1(&d_jrdy[bh][s-2]);
                    __syncthreads();
                }

                // epilogue-state prefetch (hf0 only): issue early, use later
                const int kkb = g*256 + h0 + q4;
                const int o1  = p1*131072 + bb*1024 + kkb;
                us4 pf_hhi{}, pf_hlo{};
                if (hf == 0) { pf_hhi = ald8v(U + HM_HI + o1); pf_hlo = ald8v(U + HM_LO + o1); }

                // ---- h-part (K=256), agent-scoped state loads (full hi/lo) ----
                {
                    const int hofs = p1*131072 + bb*1024 + g*256;
                    #pragma unroll 2
                    for (int i = 0; i < 8; ++i) {
                        short8 hhi = ald16(U + HM_HI + hofs + i*32 + ko8);
                        short8 hlo = ald16(U + HM_LO + hofs + i*32 + ko8);
                        short8 whi = *(const short8*)(lds_us + M_WHH_HI + (rAw + r16)*264 + i*32 + ko8);
                        short8 wlo = *(const short8*)(lds_us + M_WHH_LO + (rAw + r16)*264 + i*32 + ko8);
                        aA0 = MFMA16(whi, hhi, aA0);
                        aA1 = MFMA16(whi, hlo, aA1);
                        aA2 = MFMA16(wlo, hhi, aA2);
                        if (hf == 1) {
                            short8 nhi = *(const short8*)(lds_us + M_WHH_HI + (32 + r16)*264 + i*32 + ko8);
                            short8 nlo = *(const short8*)(lds_us + M_WHH_LO + (32 + r16)*264 + i*32 + ko8);
                            aB0 = MFMA16(nhi, hhi, aB0);
                            aB1 = MFMA16(nhi, hlo, aB1);
                            aB2 = MFMA16(nlo, hhi, aB2);
                        }
                    }
                }
                f32x4 accA = aA0 + aA1 + aA2;
                f32x4 accB = aB0 + aB1 + aB2;

                if (hf == 1) {
                    #pragma unroll
                    for (int r = 0; r < 4; ++r) {
                        int idx = (q4 + r)*16 + r16;
                        exch[(tb*2 + 0)*256 + idx] = accA[r];   // z partial
                        exch[(tb*2 + 1)*256 + idx] = accB[r];   // hn partial
                    }
                }
                __syncthreads();
                if (hf == 0) {
                    const int o0 = p0*131072 + bb*1024 + kkb;
                    us4 hmhi, hmlo, nghi, nglo;
                    #pragma unroll
                    for (int r = 0; r < 4; ++r) {
                        int idx = (q4 + r)*16 + r16;
                        float zacc  = exch[(tb*2 + 0)*256 + idx];
                        float hnacc = exch[(tb*2 + 1)*256 + idx];
                        float rg = sigf(accA[r] + br_[r]);
                        float zg = sigf(zacc + bz_[r]);
                        float n  = tanhfast(accB[r] + bn_[r] + rg * hnacc);
                        float hmo = bf2f(pf_hhi[r]) + bf2f(pf_hlo[r]);
                        float hnew = n + zg * (hmo - n);
                        unsigned short h1 = f2bf(hnew);
                        hmhi[r] = h1; hmlo[r] = f2bf(hnew - bf2f(h1));
                        unsigned short h2 = f2bf(n);
                        nghi[r] = h2; nglo[r] = f2bf(n - bf2f(h2));
                    }
                    ast8(U + HM_HI + o0, hmhi);
                    ast8(U + HM_LO + o0, hmlo);
                    ast8(U + NG_HI + o0, nghi);
                    ast8(U + NG_LO + o0, nglo);
                }
                __syncthreads();   // drains vmcnt: scoped stores complete at L3
                if (coop && tid == 0) {
                    int old = atomicAdd(&d_mcnt[bh][g][s], 1);
                    if (old == 15)
                        __hip_atomic_store(&d_mrdy[bh][g][s], 1,
                                           __ATOMIC_RELAXED, __HIP_MEMORY_SCOPE_AGENT);
                }
            }
        }
    } else {
        // ============ JOINT: block = 16 j-rows x 64 batch, 1 step behind ====
        const int wg2 = wg - 128;
        const int j0  = (wg2 >> 1) * 16;
        const int bh  = wg2 & 1;
        const int bb  = bh*64 + tb*16 + r16;
        float* exch = (float*)(lds_us + J_EX_US);

        // ---- stage weights to LDS as hi/lo ----
        for (int i = tid; i < 16*1024; i += NTHR) {
            int r = i >> 10, k = i & 1023;
            float v = u_c[(size_t)(j0 + r)*1024 + k];
            unsigned short h = f2bf(v);
            lds_us[J_UC_HI + r*1032 + k] = h;
            lds_us[J_UC_LO + r*1032 + k] = f2bf(v - bf2f(h));
            v = u_z[(size_t)(j0 + r)*1024 + k];
            h = f2bf(v);
            lds_us[J_UZ_HI + r*1032 + k] = h;
            lds_us[J_UZ_LO + r*1032 + k] = f2bf(v - bf2f(h));
        }
        for (int i = tid; i < 16*256; i += NTHR) {
            int r = i >> 8, k = i & 255;
            float v = w_z[(size_t)(j0 + r)*256 + k];
            unsigned short h = f2bf(v);
            lds_us[J_WZ_HI + r*264 + k] = h;
            lds_us[J_WZ_LO + r*264 + k] = f2bf(v - bf2f(h));
        }
        __syncthreads();
        if (coop) { grid.sync(); __threadfence(); }   // one-time: init visibility

        float bc_[4], bzj_[4];
        #pragma unroll
        for (int r = 0; r < 4; ++r) {
            int jj = j0 + q4 + r;
            bc_[r]  = b_c[jj];
            bzj_[r] = b_z[jj];
        }

        for (int s = s_lo; s <= s_hi; ++s) {
            if (s >= 1) {
                const int u  = s - 1;
                const int p0 = u & 1, p1 = (u+1) & 1;
                f32x4 a0={0.f,0.f,0.f,0.f}, a1={0.f,0.f,0.f,0.f}, a2={0.f,0.f,0.f,0.f};

                // ---- w_z · x (K=256, pre-spin, hf1) — full 3-term (x is fp32) ----
                if (hf == 1) {
                    const float* xp = x + ((size_t)u*128 + bb)*256;
                    #pragma unroll 2
                    for (int i = 0; i < 8; ++i) {
                        short8 xhi, xlo; cvt8_hilo(xp + i*32 + ko8, xhi, xlo);
                        short8 whi = *(const short8*)(lds_us + J_WZ_HI + r16*264 + i*32 + ko8);
                        short8 wlo = *(const short8*)(lds_us + J_WZ_LO + r16*264 + i*32 + ko8);
                        a0 = MFMA16(whi, xhi, a0);
                        a1 = MFMA16(whi, xlo, a1);
                        a2 = MFMA16(wlo, xhi, a2);
                    }
                }

                if (coop) {
                    if (tid < 4) spin1(&d_mrdy[bh][tid][u]);      // lane-parallel
                    if (tid == 4 && u >= 1) spin1(&d_jrdy[bh][u-1]);
                    __syncthreads();
                }

                // epilogue-state prefetch (hf0 only)
                const int jb = j0 + q4;
                const int o1 = p1*131072 + bb*1024 + jb;
                us4 pf_hhi{}, pf_hlo{};
                if (hf == 0) { pf_hhi = ald8v(U + HJ_HI + o1); pf_hlo = ald8v(U + HJ_LO + o1); }

                // ---- K=1024: u_c·ng(u) (hf0) or u_z·hj(u-1) (hf1) ----
                // ACT = HI plane only (single bf16): act-rounding is per-step noise,
                // damped by the contractive hj chain (zj<1). Weight LO term kept
                // (weight rounding = correlated bias — the round-3..13 killer).
                {
                    const int aHI = (hf ? (HJ_HI + p1*131072) : (NG_HI + p0*131072)) + bb*1024;
                    const int wHI = (hf ? J_UZ_HI : J_UC_HI) + r16*1032;
                    const int wLO = (hf ? J_UZ_LO : J_UC_LO) + r16*1032;
                    #pragma unroll 4
                    for (int i = 0; i < 32; ++i) {
                        short8 ahi = ald16(U + aHI + i*32 + ko8);
                        short8 whi = *(const short8*)(lds_us + wHI + i*32 + ko8);
                        short8 wlo = *(const short8*)(lds_us + wLO + i*32 + ko8);
                        a0 = MFMA16(whi, ahi, a0);
                        a2 = MFMA16(wlo, ahi, a2);
                    }
                }
                f32x4 acc = a0 + a1 + a2;

                if (hf == 1) {
                    #pragma unroll
                    for (int r = 0; r < 4; ++r) {
                        int idx = (q4 + r)*16 + r16;
                        exch[tb*256 + idx] = acc[r];            // zj partial
                    }
                }
                __syncthreads();
                if (hf == 0) {
                    const int o0 = p0*131072 + bb*1024 + jb;
                    us4 hjhi, hjlo;
                    float hv[4];
                    #pragma unroll
                    for (int r = 0; r < 4; ++r) {
                        int idx = (q4 + r)*16 + r16;
                        float zacc = exch[tb*256 + idx];
                        float cg_  = tanhfast(acc[r] + bc_[r]);
                        float zj   = sigf(zacc + bzj_[r]);
                        float hjo  = bf2f(pf_hhi[r]) + bf2f(pf_hlo[r]);
                        float hnew = cg_ + zj * (hjo - cg_);
                        unsigned short h1 = f2bf(hnew);
                        hjhi[r] = h1; hjlo[r] = f2bf(hnew - bf2f(h1));
                        hv[r] = hnew;
                    }
                    ast8(U + HJ_HI + o0, hjhi);
                    ast8(U + HJ_LO + o0, hjlo);
                    if (u == Tn-1) {
                        float4 o; o.x=hv[0]; o.y=hv[1]; o.z=hv[2]; o.w=hv[3];
                        *(float4*)(out + (size_t)bb*1024 + jb) = o;
                    }
                }
                __syncthreads();   // drains vmcnt: scoped stores complete at L3
                if (coop && tid == 0) {
                    int old = atomicAdd(&d_jcnt[bh][u], 1);
                    if (old == 63)
                        __hip_atomic_store(&d_jrdy[bh][u], 1,
                                           __ATOMIC_RELAXED, __HIP_MEMORY_SCOPE_AGENT);
                }
            }
        }
    }
}

extern "C" void kernel_launch(void* const* d_in, const int* in_sizes, int n_in,
                              void* d_out, int out_size, void* d_ws, size_t ws_size,
                              hipStream_t stream) {
    const float* x    = (const float*)d_in[0];
    const float* w_ih = (const float*)d_in[1];
    const float* w_hh = (const float*)d_in[2];
    const float* b_ih = (const float*)d_in[3];
    const float* u_c  = (const float*)d_in[4];
    const float* b_c  = (const float*)d_in[5];
    const float* w_z  = (const float*)d_in[6];
    const float* u_z  = (const float*)d_in[7];
    const float* b_z  = (const float*)d_in[8];
    float* out = (float*)d_out;
    float* ws  = (float*)d_ws;

    (void)hipFuncSetAttribute((const void*)mgrn_k,
                              hipFuncAttributeMaxDynamicSharedMemorySize,
                              LDS_BYTES);

    // Residency guard: only the cooperative path if the whole grid fits.
    int maxb = 0;
    hipError_t qe = hipOccupancyMaxActiveBlocksPerMultiprocessor(
                        &maxb, (const void*)mgrn_k, NTHR, (size_t)LDS_BYTES);
    bool can_coop = (qe == hipSuccess) && (maxb * 256 >= NBLK);

    int s_lo = 0, s_hi = Tn, coop = 1;
    void* args[] = {&x, &w_ih, &w_hh, &b_ih, &u_c, &b_c, &w_z, &u_z, &b_z,
                    &out, &ws, &s_lo, &s_hi, &coop};
    hipError_t e = hipErrorUnknown;
    if (can_coop)
        e = hipLaunchCooperativeKernel((void*)mgrn_k, dim3(NBLK), dim3(NTHR),
                                       args, LDS_BYTES, stream);
    if (e != hipSuccess) {
        (void)hipGetLastError();   // clear sticky error
        hipMemsetAsync(ws, 0, (size_t)786432 * sizeof(float), stream);
        for (int s = 0; s <= Tn; ++s) {
            mgrn_k<<<dim3(NBLK), dim3(NTHR), LDS_BYTES, stream>>>(
                x, w_ih, w_hh, b_ih, u_c, b_c, w_z, u_z, b_z, out, ws, s, s, 0);
        }
    }
}